// Round 5
// baseline (465.086 us; speedup 1.0000x reference)
//
#include <hip/hip_runtime.h>

#define N_TOT  200000
#define NG_    100000
#define NU_    100000
#define E_CNT  3200000
#define C_CNT  1000000

#define NBUCK  196        // ceil(NG_/512): bucket k covers nodes [k*512, k*512+512)
#define NBLK   256        // edge chunks
#define CHUNK  12500      // E_CNT / NBLK exactly

// ---- Phase A: per-(chunk,bucket) histogram, LDS-only atomics ----
__global__ __launch_bounds__(256) void phaseA(const int* __restrict__ dst,
                                              int* __restrict__ cnt_mat) {
    __shared__ int hcnt[NBUCK];
    int t = threadIdx.x;
    if (t < NBUCK) hcnt[t] = 0;
    __syncthreads();
    int beg = blockIdx.x * CHUNK, end = beg + CHUNK;
    for (int e = beg + t; e < end; e += 256)
        atomicAdd(&hcnt[dst[e] >> 9], 1);
    __syncthreads();
    if (t < NBUCK) cnt_mat[blockIdx.x * NBUCK + t] = hcnt[t];
}

// ---- Phase B1: per-column (bucket) exclusive scan over chunks ----
__global__ __launch_bounds__(256) void phaseB1(const int* __restrict__ cnt_mat,
                                               int* __restrict__ off_mat,
                                               int* __restrict__ colsum) {
    __shared__ int s[256];
    int t = threadIdx.x;          // chunk index
    int k = blockIdx.x;           // bucket index
    int v = cnt_mat[t * NBUCK + k];
    s[t] = v;
    __syncthreads();
    for (int off = 1; off < 256; off <<= 1) {
        int u = (t >= off) ? s[t - off] : 0;
        __syncthreads();
        s[t] += u;
        __syncthreads();
    }
    off_mat[t * NBUCK + k] = s[t] - v;     // exclusive within column
    if (t == 255) colsum[k] = s[255];
}

// ---- Phase B2: exclusive scan of bucket totals -> bbase[0..NBUCK] ----
__global__ __launch_bounds__(256) void phaseB2(const int* __restrict__ colsum,
                                               int* __restrict__ bbase) {
    __shared__ int s[256];
    int t = threadIdx.x;
    int v = (t < NBUCK) ? colsum[t] : 0;
    s[t] = v;
    __syncthreads();
    for (int off = 1; off < 256; off <<= 1) {
        int u = (t >= off) ? s[t - off] : 0;
        __syncthreads();
        s[t] += u;
        __syncthreads();
    }
    if (t < NBUCK) bbase[t] = s[t] - v;
    if (t == NBUCK - 1) bbase[NBUCK] = s[t];
}

// ---- Phase C: bucket-scatter packed (src<<9 | bin); LDS-only atomics ----
__global__ __launch_bounds__(256) void phaseC(const int* __restrict__ src,
                                              const int* __restrict__ dst,
                                              const int* __restrict__ off_mat,
                                              const int* __restrict__ bbase,
                                              int* __restrict__ pairs) {
    __shared__ int loc[NBUCK];
    int t = threadIdx.x;
    if (t < NBUCK) loc[t] = bbase[t] + off_mat[blockIdx.x * NBUCK + t];
    __syncthreads();
    int beg = blockIdx.x * CHUNK, end = beg + CHUNK;
    for (int e = beg + t; e < end; e += 256) {
        int d = dst[e], s = src[e];
        int k = d >> 9;
        int pos = atomicAdd(&loc[k], 1);
        pairs[pos] = (s << 9) | (d & 511);
    }
}

// ---- conv1: 4 blocks/bucket, each owns a 128-bin quarter ----
__global__ __launch_bounds__(256) void conv1_kernel(const int* __restrict__ bbase,
                                                    const int* __restrict__ pairs,
                                                    const float* __restrict__ x,
                                                    const float* __restrict__ w_rel,
                                                    const float* __restrict__ w_root,
                                                    const float* __restrict__ b,
                                                    float* __restrict__ h1) {
    __shared__ float acc[128 * 3];
    int t = threadIdx.x;
    int k = blockIdx.x >> 2, q = blockIdx.x & 3;
    if (t < 128) { acc[3*t] = 0.f; acc[3*t+1] = 0.f; acc[3*t+2] = 0.f; }
    __syncthreads();
    int beg = bbase[k], end = bbase[k + 1];
    int e = beg + t;
    for (; e + 768 < end; e += 1024) {
        int p0 = pairs[e], p1 = pairs[e + 256], p2 = pairs[e + 512], p3 = pairs[e + 768];
        bool m0 = ((p0 >> 7) & 3) == q, m1 = ((p1 >> 7) & 3) == q;
        bool m2 = ((p2 >> 7) & 3) == q, m3 = ((p3 >> 7) & 3) == q;
        float2 v0, v1, v2, v3;
        if (m0) v0 = *(const float2*)(x + 2 * (p0 >> 9));
        if (m1) v1 = *(const float2*)(x + 2 * (p1 >> 9));
        if (m2) v2 = *(const float2*)(x + 2 * (p2 >> 9));
        if (m3) v3 = *(const float2*)(x + 2 * (p3 >> 9));
        if (m0) { float* ap = &acc[3 * (p0 & 127)]; atomicAdd(ap, v0.x); atomicAdd(ap + 1, v0.y); }
        if (m1) { float* ap = &acc[3 * (p1 & 127)]; atomicAdd(ap, v1.x); atomicAdd(ap + 1, v1.y); }
        if (m2) { float* ap = &acc[3 * (p2 & 127)]; atomicAdd(ap, v2.x); atomicAdd(ap + 1, v2.y); }
        if (m3) { float* ap = &acc[3 * (p3 & 127)]; atomicAdd(ap, v3.x); atomicAdd(ap + 1, v3.y); }
    }
    for (; e < end; e += 256) {
        int p = pairs[e];
        if (((p >> 7) & 3) == q) {
            float2 v = *(const float2*)(x + 2 * (p >> 9));
            float* ap = &acc[3 * (p & 127)];
            atomicAdd(ap, v.x); atomicAdd(ap + 1, v.y);
        }
    }
    __syncthreads();
    if (t < 128) {
        int i = (k << 9) + (q << 7) + t;
        if (i < NG_) {
            float a0 = acc[3*t], a1 = acc[3*t+1];
            float2 xi = *(const float2*)(x + 2 * i);
#pragma unroll
            for (int j = 0; j < 8; j++) {
                float v = a0 * w_rel[j] + a1 * w_rel[8 + j]
                        + xi.x * w_root[j] + xi.y * w_root[8 + j] + b[j];
                h1[8 * i + j] = fmaxf(v, 0.f);
            }
        }
    }
}

// ---- conv2: 4 blocks/bucket, each owns a 128-bin quarter ----
__global__ __launch_bounds__(256) void conv2_kernel(const int* __restrict__ bbase,
                                                    const int* __restrict__ pairs,
                                                    const float* __restrict__ h1,
                                                    const float* __restrict__ w_rel,
                                                    const float* __restrict__ w_root,
                                                    const float* __restrict__ b,
                                                    float* __restrict__ h2) {
    __shared__ float acc[128 * 9];   // 4.6 KB, stride 9 coprime with 32 banks
    int t = threadIdx.x;
    int k = blockIdx.x >> 2, q = blockIdx.x & 3;
    for (int i = t; i < 128 * 9; i += 256) acc[i] = 0.f;
    __syncthreads();
    int beg = bbase[k], end = bbase[k + 1];
    int e = beg + t;
    for (; e + 768 < end; e += 1024) {
        int p0 = pairs[e], p1 = pairs[e + 256], p2 = pairs[e + 512], p3 = pairs[e + 768];
        bool m0 = ((p0 >> 7) & 3) == q, m1 = ((p1 >> 7) & 3) == q;
        bool m2 = ((p2 >> 7) & 3) == q, m3 = ((p3 >> 7) & 3) == q;
        float4 a0, b0, a1, b1, a2, b2, a3, b3;
        if (m0) { const float4* hp = (const float4*)(h1 + 8 * (p0 >> 9)); a0 = hp[0]; b0 = hp[1]; }
        if (m1) { const float4* hp = (const float4*)(h1 + 8 * (p1 >> 9)); a1 = hp[0]; b1 = hp[1]; }
        if (m2) { const float4* hp = (const float4*)(h1 + 8 * (p2 >> 9)); a2 = hp[0]; b2 = hp[1]; }
        if (m3) { const float4* hp = (const float4*)(h1 + 8 * (p3 >> 9)); a3 = hp[0]; b3 = hp[1]; }
        if (m0) { float* ap = &acc[9 * (p0 & 127)];
            atomicAdd(ap+0,a0.x); atomicAdd(ap+1,a0.y); atomicAdd(ap+2,a0.z); atomicAdd(ap+3,a0.w);
            atomicAdd(ap+4,b0.x); atomicAdd(ap+5,b0.y); atomicAdd(ap+6,b0.z); atomicAdd(ap+7,b0.w); }
        if (m1) { float* ap = &acc[9 * (p1 & 127)];
            atomicAdd(ap+0,a1.x); atomicAdd(ap+1,a1.y); atomicAdd(ap+2,a1.z); atomicAdd(ap+3,a1.w);
            atomicAdd(ap+4,b1.x); atomicAdd(ap+5,b1.y); atomicAdd(ap+6,b1.z); atomicAdd(ap+7,b1.w); }
        if (m2) { float* ap = &acc[9 * (p2 & 127)];
            atomicAdd(ap+0,a2.x); atomicAdd(ap+1,a2.y); atomicAdd(ap+2,a2.z); atomicAdd(ap+3,a2.w);
            atomicAdd(ap+4,b2.x); atomicAdd(ap+5,b2.y); atomicAdd(ap+6,b2.z); atomicAdd(ap+7,b2.w); }
        if (m3) { float* ap = &acc[9 * (p3 & 127)];
            atomicAdd(ap+0,a3.x); atomicAdd(ap+1,a3.y); atomicAdd(ap+2,a3.z); atomicAdd(ap+3,a3.w);
            atomicAdd(ap+4,b3.x); atomicAdd(ap+5,b3.y); atomicAdd(ap+6,b3.z); atomicAdd(ap+7,b3.w); }
    }
    for (; e < end; e += 256) {
        int p = pairs[e];
        if (((p >> 7) & 3) == q) {
            const float4* hp = (const float4*)(h1 + 8 * (p >> 9));
            float4 v0 = hp[0], v1 = hp[1];
            float* ap = &acc[9 * (p & 127)];
            atomicAdd(ap+0,v0.x); atomicAdd(ap+1,v0.y); atomicAdd(ap+2,v0.z); atomicAdd(ap+3,v0.w);
            atomicAdd(ap+4,v1.x); atomicAdd(ap+5,v1.y); atomicAdd(ap+6,v1.z); atomicAdd(ap+7,v1.w);
        }
    }
    __syncthreads();
    if (t < 128) {
        int i = (k << 9) + (q << 7) + t;
        if (i < NG_) {
            float a[8], h[8];
#pragma unroll
            for (int j = 0; j < 8; j++) a[j] = acc[9 * t + j];
            const float4* hp = (const float4*)(h1 + 8 * i);
            float4 t0 = hp[0], t1 = hp[1];
            h[0]=t0.x; h[1]=t0.y; h[2]=t0.z; h[3]=t0.w;
            h[4]=t1.x; h[5]=t1.y; h[6]=t1.z; h[7]=t1.w;
#pragma unroll
            for (int kk = 0; kk < 16; kk++) {
                float v = b[kk];
#pragma unroll
                for (int j = 0; j < 8; j++)
                    v += a[j] * w_rel[j * 16 + kk] + h[j] * w_root[j * 16 + kk];
                h2[16 * i + kk] = fmaxf(v, 0.f);
            }
        }
    }
}

// ---- final MLP, xu projection fused in ----
__global__ __launch_bounds__(256) void final_mlp(const int* __restrict__ cand,
                                                 const float* __restrict__ h2,
                                                 const float* __restrict__ x,
                                                 const float* __restrict__ wu,
                                                 const float* __restrict__ bu,
                                                 const float* __restrict__ wa,
                                                 const float* __restrict__ ba,
                                                 const float* __restrict__ wb,
                                                 const float* __restrict__ bb,
                                                 float* __restrict__ out) {
    __shared__ float s_waT[64 * 32];   // s_waT[j][i] = wa[i*64 + j]
    __shared__ float s_ba[64];
    __shared__ float s_wb[64];
    __shared__ float s_wu[32];
    __shared__ float s_bu[16];
    int t = threadIdx.x;
    for (int idx = t; idx < 2048; idx += blockDim.x) {
        int j = idx >> 5, i = idx & 31;
        s_waT[idx] = wa[i * 64 + j];
    }
    if (t < 64) { s_ba[t] = ba[t]; s_wb[t] = wb[t]; }
    if (t < 32) s_wu[t] = wu[t];
    if (t < 16) s_bu[t] = bu[t];
    __syncthreads();

    int c = blockIdx.x * blockDim.x + t;
    if (c >= C_CNT) return;
    int g = cand[2 * c], u = cand[2 * c + 1];

    float ec[32];
    const float4* hp = (const float4*)(h2 + 16 * g);
#pragma unroll
    for (int q = 0; q < 4; q++) {
        float4 v = hp[q];
        ec[4*q] = v.x; ec[4*q+1] = v.y; ec[4*q+2] = v.z; ec[4*q+3] = v.w;
    }
    float2 xv = *(const float2*)(x + 2 * (NG_ + u));
#pragma unroll
    for (int k = 0; k < 16; k++)
        ec[16 + k] = xv.x * s_wu[k] + xv.y * s_wu[16 + k] + s_bu[k];

    float acc = bb[0];
#pragma unroll 8
    for (int j = 0; j < 64; j++) {
        const float4* wp = (const float4*)&s_waT[j * 32];
        float v = s_ba[j];
#pragma unroll
        for (int q = 0; q < 8; q++) {
            float4 w = wp[q];
            v += ec[4*q] * w.x + ec[4*q+1] * w.y + ec[4*q+2] * w.z + ec[4*q+3] * w.w;
        }
        acc += fmaxf(v, 0.f) * s_wb[j];
    }
    out[c] = acc;
}

// ======================= launch =======================

extern "C" void kernel_launch(void* const* d_in, const int* in_sizes, int n_in,
                              void* d_out, int out_size, void* d_ws, size_t ws_size,
                              hipStream_t stream) {
    const float* x      = (const float*)d_in[0];
    const int*   cand   = (const int*)d_in[2];
    const int*   edges  = (const int*)d_in[3];   // [2, E]: src then dst
    const float* w1_rel = (const float*)d_in[4];
    const float* w1_root= (const float*)d_in[5];
    const float* b1     = (const float*)d_in[6];
    const float* w2_rel = (const float*)d_in[7];
    const float* w2_root= (const float*)d_in[8];
    const float* b2     = (const float*)d_in[9];
    const float* wu     = (const float*)d_in[10];
    const float* bu     = (const float*)d_in[11];
    const float* wa     = (const float*)d_in[12];
    const float* ba     = (const float*)d_in[13];
    const float* wb     = (const float*)d_in[14];
    const float* bb     = (const float*)d_in[15];
    float* out = (float*)d_out;

    const int* src = edges;
    const int* dst = edges + E_CNT;

    // ws layout (int units) — unchanged from round 4 (22.8 MB):
    int* ws_i = (int*)d_ws;
    int*   cnt_mat = ws_i;
    int*   off_mat = ws_i + 50176;
    int*   colsum  = ws_i + 100352;
    int*   bbase   = ws_i + 100608;
    int*   pairs   = ws_i + 100864;
    float* h1      = (float*)(ws_i + 3300864);
    float* h2      = (float*)(ws_i + 4100864);

    dim3 blk256(256);

    phaseA <<<NBLK, blk256, 0, stream>>>(dst, cnt_mat);
    phaseB1<<<NBUCK, blk256, 0, stream>>>(cnt_mat, off_mat, colsum);
    phaseB2<<<1, blk256, 0, stream>>>(colsum, bbase);
    phaseC <<<NBLK, blk256, 0, stream>>>(src, dst, off_mat, bbase, pairs);
    conv1_kernel<<<NBUCK * 4, blk256, 0, stream>>>(bbase, pairs, x, w1_rel, w1_root, b1, h1);
    conv2_kernel<<<NBUCK * 4, blk256, 0, stream>>>(bbase, pairs, h1, w2_rel, w2_root, b2, h2);
    final_mlp<<<(C_CNT + 255) / 256, blk256, 0, stream>>>(cand, h2, x, wu, bu, wa, ba, wb, bb, out);
}

// Round 6
// 459.451 us; speedup vs baseline: 1.0123x; 1.0123x over previous
//
#include <hip/hip_runtime.h>

#define N_TOT  200000
#define NG_    100000
#define NU_    100000
#define E_CNT  3200000
#define C_CNT  1000000

#define NBUCK  196        // ceil(NG_/512): bucket k covers nodes [k*512, k*512+512)
#define NBLK   256        // edge chunks
#define CHUNK  12500      // E_CNT / NBLK exactly

// ---- Phase A: per-(chunk,bucket) histogram, LDS-only atomics ----
__global__ __launch_bounds__(256) void phaseA(const int* __restrict__ dst,
                                              int* __restrict__ cnt_mat) {
    __shared__ int hcnt[NBUCK];
    int t = threadIdx.x;
    if (t < NBUCK) hcnt[t] = 0;
    __syncthreads();
    int beg = blockIdx.x * CHUNK, end = beg + CHUNK;
    for (int e = beg + t; e < end; e += 256)
        atomicAdd(&hcnt[dst[e] >> 9], 1);
    __syncthreads();
    if (t < NBUCK) cnt_mat[blockIdx.x * NBUCK + t] = hcnt[t];
}

// ---- Phase B1: per-column (bucket) exclusive scan over chunks ----
__global__ __launch_bounds__(256) void phaseB1(const int* __restrict__ cnt_mat,
                                               int* __restrict__ off_mat,
                                               int* __restrict__ colsum) {
    __shared__ int s[256];
    int t = threadIdx.x;          // chunk index
    int k = blockIdx.x;           // bucket index
    int v = cnt_mat[t * NBUCK + k];
    s[t] = v;
    __syncthreads();
    for (int off = 1; off < 256; off <<= 1) {
        int u = (t >= off) ? s[t - off] : 0;
        __syncthreads();
        s[t] += u;
        __syncthreads();
    }
    off_mat[t * NBUCK + k] = s[t] - v;     // exclusive within column
    if (t == 255) colsum[k] = s[255];
}

// ---- Phase B2: exclusive scan of bucket totals -> bbase[0..NBUCK] ----
__global__ __launch_bounds__(256) void phaseB2(const int* __restrict__ colsum,
                                               int* __restrict__ bbase) {
    __shared__ int s[256];
    int t = threadIdx.x;
    int v = (t < NBUCK) ? colsum[t] : 0;
    s[t] = v;
    __syncthreads();
    for (int off = 1; off < 256; off <<= 1) {
        int u = (t >= off) ? s[t - off] : 0;
        __syncthreads();
        s[t] += u;
        __syncthreads();
    }
    if (t < NBUCK) bbase[t] = s[t] - v;
    if (t == NBUCK - 1) bbase[NBUCK] = s[t];
}

// ---- Phase C: bucket-scatter packed (src<<9 | bin); LDS-only atomics ----
__global__ __launch_bounds__(256) void phaseC(const int* __restrict__ src,
                                              const int* __restrict__ dst,
                                              const int* __restrict__ off_mat,
                                              const int* __restrict__ bbase,
                                              int* __restrict__ pairs) {
    __shared__ int loc[NBUCK];
    int t = threadIdx.x;
    if (t < NBUCK) loc[t] = bbase[t] + off_mat[blockIdx.x * NBUCK + t];
    __syncthreads();
    int beg = blockIdx.x * CHUNK, end = beg + CHUNK;
    for (int e = beg + t; e < end; e += 256) {
        int d = dst[e], s = src[e];
        int k = d >> 9;
        int pos = atomicAdd(&loc[k], 1);
        pairs[pos] = (s << 9) | (d & 511);
    }
}

// ---- conv1: 1 block/bucket, 2 lanes per edge -> 1 LDS atomic per lane ----
__global__ __launch_bounds__(1024) void conv1_kernel(const int* __restrict__ bbase,
                                                     const int* __restrict__ pairs,
                                                     const float* __restrict__ x,
                                                     const float* __restrict__ w_rel,
                                                     const float* __restrict__ w_root,
                                                     const float* __restrict__ b,
                                                     float* __restrict__ h1) {
    __shared__ float acc[512 * 3];   // stride 3 coprime with 32 banks
    int t = threadIdx.x, k = blockIdx.x;
    for (int i = t; i < 512 * 3; i += 1024) acc[i] = 0.f;
    __syncthreads();
    int beg = bbase[k], end = bbase[k + 1];
    int sub = t & 1;           // feature index (0..1)
    int eg  = t >> 1;          // edge slot (0..511)
    int e = beg + eg;
    for (; e + 512 < end; e += 1024) {
        int p0 = pairs[e], p1 = pairs[e + 512];
        float v0 = x[2 * (p0 >> 9) + sub];
        float v1 = x[2 * (p1 >> 9) + sub];
        atomicAdd(&acc[3 * (p0 & 511) + sub], v0);
        atomicAdd(&acc[3 * (p1 & 511) + sub], v1);
    }
    for (; e < end; e += 512) {
        int p = pairs[e];
        atomicAdd(&acc[3 * (p & 511) + sub], x[2 * (p >> 9) + sub]);
    }
    __syncthreads();
    if (t < 512) {
        int i = (k << 9) + t;
        if (i < NG_) {
            float a0 = acc[3 * t], a1 = acc[3 * t + 1];
            float2 xi = *(const float2*)(x + 2 * i);
#pragma unroll
            for (int j = 0; j < 8; j++) {
                float v = a0 * w_rel[j] + a1 * w_rel[8 + j]
                        + xi.x * w_root[j] + xi.y * w_root[8 + j] + b[j];
                h1[8 * i + j] = fmaxf(v, 0.f);
            }
        }
    }
}

// ---- conv2: 1 block/bucket, 8 lanes per edge -> 1 LDS atomic per lane ----
__global__ __launch_bounds__(1024) void conv2_kernel(const int* __restrict__ bbase,
                                                     const int* __restrict__ pairs,
                                                     const float* __restrict__ h1,
                                                     const float* __restrict__ w_rel,
                                                     const float* __restrict__ w_root,
                                                     const float* __restrict__ b,
                                                     float* __restrict__ h2) {
    __shared__ float acc[512 * 9];   // 18 KB, stride 9 coprime with 32 banks
    int t = threadIdx.x, k = blockIdx.x;
    for (int i = t; i < 512 * 9; i += 1024) acc[i] = 0.f;
    __syncthreads();
    int beg = bbase[k], end = bbase[k + 1];
    int sub = t & 7;           // feature index (0..7)
    int eg  = t >> 3;          // edge slot (0..127)
    int e = beg + eg;
    for (; e + 384 < end; e += 512) {
        int p0 = pairs[e], p1 = pairs[e + 128], p2 = pairs[e + 256], p3 = pairs[e + 384];
        float v0 = h1[8 * (p0 >> 9) + sub];
        float v1 = h1[8 * (p1 >> 9) + sub];
        float v2 = h1[8 * (p2 >> 9) + sub];
        float v3 = h1[8 * (p3 >> 9) + sub];
        atomicAdd(&acc[9 * (p0 & 511) + sub], v0);
        atomicAdd(&acc[9 * (p1 & 511) + sub], v1);
        atomicAdd(&acc[9 * (p2 & 511) + sub], v2);
        atomicAdd(&acc[9 * (p3 & 511) + sub], v3);
    }
    for (; e < end; e += 128) {
        int p = pairs[e];
        atomicAdd(&acc[9 * (p & 511) + sub], h1[8 * (p >> 9) + sub]);
    }
    __syncthreads();
    if (t < 512) {
        int i = (k << 9) + t;
        if (i < NG_) {
            float a[8], h[8];
#pragma unroll
            for (int j = 0; j < 8; j++) a[j] = acc[9 * t + j];
            const float4* hp = (const float4*)(h1 + 8 * i);
            float4 t0 = hp[0], t1 = hp[1];
            h[0]=t0.x; h[1]=t0.y; h[2]=t0.z; h[3]=t0.w;
            h[4]=t1.x; h[5]=t1.y; h[6]=t1.z; h[7]=t1.w;
#pragma unroll
            for (int kk = 0; kk < 16; kk++) {
                float v = b[kk];
#pragma unroll
                for (int j = 0; j < 8; j++)
                    v += a[j] * w_rel[j * 16 + kk] + h[j] * w_root[j * 16 + kk];
                h2[16 * i + kk] = fmaxf(v, 0.f);
            }
        }
    }
}

// ---- final MLP, xu projection fused in ----
__global__ __launch_bounds__(256) void final_mlp(const int* __restrict__ cand,
                                                 const float* __restrict__ h2,
                                                 const float* __restrict__ x,
                                                 const float* __restrict__ wu,
                                                 const float* __restrict__ bu,
                                                 const float* __restrict__ wa,
                                                 const float* __restrict__ ba,
                                                 const float* __restrict__ wb,
                                                 const float* __restrict__ bb,
                                                 float* __restrict__ out) {
    __shared__ float s_waT[64 * 32];   // s_waT[j][i] = wa[i*64 + j]
    __shared__ float s_ba[64];
    __shared__ float s_wb[64];
    __shared__ float s_wu[32];
    __shared__ float s_bu[16];
    int t = threadIdx.x;
    for (int idx = t; idx < 2048; idx += blockDim.x) {
        int j = idx >> 5, i = idx & 31;
        s_waT[idx] = wa[i * 64 + j];
    }
    if (t < 64) { s_ba[t] = ba[t]; s_wb[t] = wb[t]; }
    if (t < 32) s_wu[t] = wu[t];
    if (t < 16) s_bu[t] = bu[t];
    __syncthreads();

    int c = blockIdx.x * blockDim.x + t;
    if (c >= C_CNT) return;
    int g = cand[2 * c], u = cand[2 * c + 1];

    float ec[32];
    const float4* hp = (const float4*)(h2 + 16 * g);
#pragma unroll
    for (int q = 0; q < 4; q++) {
        float4 v = hp[q];
        ec[4*q] = v.x; ec[4*q+1] = v.y; ec[4*q+2] = v.z; ec[4*q+3] = v.w;
    }
    float2 xv = *(const float2*)(x + 2 * (NG_ + u));
#pragma unroll
    for (int k = 0; k < 16; k++)
        ec[16 + k] = xv.x * s_wu[k] + xv.y * s_wu[16 + k] + s_bu[k];

    float acc = bb[0];
#pragma unroll 8
    for (int j = 0; j < 64; j++) {
        const float4* wp = (const float4*)&s_waT[j * 32];
        float v = s_ba[j];
#pragma unroll
        for (int q = 0; q < 8; q++) {
            float4 w = wp[q];
            v += ec[4*q] * w.x + ec[4*q+1] * w.y + ec[4*q+2] * w.z + ec[4*q+3] * w.w;
        }
        acc += fmaxf(v, 0.f) * s_wb[j];
    }
    out[c] = acc;
}

// ======================= launch =======================

extern "C" void kernel_launch(void* const* d_in, const int* in_sizes, int n_in,
                              void* d_out, int out_size, void* d_ws, size_t ws_size,
                              hipStream_t stream) {
    const float* x      = (const float*)d_in[0];
    const int*   cand   = (const int*)d_in[2];
    const int*   edges  = (const int*)d_in[3];   // [2, E]: src then dst
    const float* w1_rel = (const float*)d_in[4];
    const float* w1_root= (const float*)d_in[5];
    const float* b1     = (const float*)d_in[6];
    const float* w2_rel = (const float*)d_in[7];
    const float* w2_root= (const float*)d_in[8];
    const float* b2     = (const float*)d_in[9];
    const float* wu     = (const float*)d_in[10];
    const float* bu     = (const float*)d_in[11];
    const float* wa     = (const float*)d_in[12];
    const float* ba     = (const float*)d_in[13];
    const float* wb     = (const float*)d_in[14];
    const float* bb     = (const float*)d_in[15];
    float* out = (float*)d_out;

    const int* src = edges;
    const int* dst = edges + E_CNT;

    // ws layout (int units) — unchanged (22.8 MB):
    int* ws_i = (int*)d_ws;
    int*   cnt_mat = ws_i;
    int*   off_mat = ws_i + 50176;
    int*   colsum  = ws_i + 100352;
    int*   bbase   = ws_i + 100608;
    int*   pairs   = ws_i + 100864;
    float* h1      = (float*)(ws_i + 3300864);
    float* h2      = (float*)(ws_i + 4100864);

    dim3 blk256(256);

    phaseA <<<NBLK, blk256, 0, stream>>>(dst, cnt_mat);
    phaseB1<<<NBUCK, blk256, 0, stream>>>(cnt_mat, off_mat, colsum);
    phaseB2<<<1, blk256, 0, stream>>>(colsum, bbase);
    phaseC <<<NBLK, blk256, 0, stream>>>(src, dst, off_mat, bbase, pairs);
    conv1_kernel<<<NBUCK, 1024, 0, stream>>>(bbase, pairs, x, w1_rel, w1_root, b1, h1);
    conv2_kernel<<<NBUCK, 1024, 0, stream>>>(bbase, pairs, h1, w2_rel, w2_root, b2, h2);
    final_mlp<<<(C_CNT + 255) / 256, blk256, 0, stream>>>(cand, h2, x, wu, bu, wa, ba, wb, bb, out);
}